// Round 7
// baseline (280.553 us; speedup 1.0000x reference)
//
#include <hip/hip_runtime.h>
#include <stdint.h>

#define D_MODEL 1024
#define NHEAD   16
#define HDIM    64
#define BATCH   2
#define SEQ     2048
#define NTOK    (BATCH*SEQ)   // 4096

typedef unsigned short u16;
typedef unsigned int   u32;
typedef __attribute__((ext_vector_type(8)))  short bf16x8;
typedef __attribute__((ext_vector_type(8)))  u16   u16x8;
typedef __attribute__((ext_vector_type(4)))  u16   u16x4;
typedef __attribute__((ext_vector_type(4)))  u32   u32x4;
typedef __attribute__((ext_vector_type(4)))  float f32x4;
typedef __attribute__((ext_vector_type(16))) float f32x16;

#if __has_builtin(__builtin_amdgcn_exp2f)
#define EXP2F __builtin_amdgcn_exp2f
#else
#define EXP2F exp2f
#endif

__device__ __forceinline__ u16 f2bf(float f) {
  uint32_t u = __float_as_uint(f);
  u += 0x7fffu + ((u >> 16) & 1u);
  return (u16)(u >> 16);
}

__device__ __forceinline__ void gl_lds16(const u16* g, u16* l) {
  __builtin_amdgcn_global_load_lds(
      (const __attribute__((address_space(1))) void*)g,
      (__attribute__((address_space(3))) void*)l, 16, 0, 0);
}

__device__ __forceinline__ u32 cvtpk(float lo, float hi) {
  u32 r;
  asm("v_cvt_pk_bf16_f32 %0, %1, %2" : "=v"(r) : "v"(lo), "v"(hi));
  return r;
}
__device__ __forceinline__ void pl32swap(u32& a, u32& b) {
  asm("v_permlane32_swap_b32 %0, %1" : "+v"(a), "+v"(b));
}

__device__ __forceinline__ f32x16 mfma32(bf16x8 a, bf16x8 b, f32x16 c) {
  return __builtin_amdgcn_mfma_f32_32x32x16_bf16(a, b, c, 0, 0, 0);
}

// ---------------- fused f32->bf16 convert for all 6 tensors + bias concat ---
__global__ __launch_bounds__(256) void cvt_all(
    const float* __restrict__ x,  const float* __restrict__ Wq,
    const float* __restrict__ Wk, const float* __restrict__ Wv,
    const float* __restrict__ W1, const float* __restrict__ W2,
    const float* __restrict__ bq, const float* __restrict__ bk,
    const float* __restrict__ bv,
    u16* __restrict__ x_bf, u16* __restrict__ wqkv,
    u16* __restrict__ w1b,  u16* __restrict__ w2b,
    float* __restrict__ bqkv) {
  const int bid = blockIdx.x, t = threadIdx.x;
  if (bid == 4608) {  // bias concat
    for (int i = t; i < 3072; i += 256)
      bqkv[i] = i < 1024 ? bq[i] : (i < 2048 ? bk[i - 1024] : bv[i - 2048]);
    return;
  }
  const float* src; u16* dst; int off;
  if (bid < 2048)      { src = x;  dst = x_bf;            off = bid; }
  else if (bid < 2560) { src = Wq; dst = wqkv;            off = bid - 2048; }
  else if (bid < 3072) { src = Wk; dst = wqkv + (1 << 20); off = bid - 2560; }
  else if (bid < 3584) { src = Wv; dst = wqkv + (2 << 20); off = bid - 3072; }
  else if (bid < 4096) { src = W1; dst = w1b;             off = bid - 3584; }
  else                 { src = W2; dst = w2b;             off = bid - 4096; }
  const int i = (off * 256 + t) * 8;
  float4 a = *(const float4*)(src + i);
  float4 b = *(const float4*)(src + i + 4);
  u16x8 o;
  o[0] = f2bf(a.x); o[1] = f2bf(a.y); o[2] = f2bf(a.z); o[3] = f2bf(a.w);
  o[4] = f2bf(b.x); o[5] = f2bf(b.y); o[6] = f2bf(b.z); o[7] = f2bf(b.w);
  *(u16x8*)(dst + i) = o;
}

// ---------------- BT GEMM: C[M,N] = A[M,K] * B[N,K]^T + bias ----------------
// 128x128 tile, BK=32, 4-deep circular LDS prefetch (stage t+3 while
// computing t). Counted vmcnt(12) + raw s_barrier -> loads stay in flight
// across barriers (no vmcnt(0) drain; T3/T4). Buffer reuse distance = 3
// iterations; exactly one lgkmcnt(0)+barrier between a buffer's last
// ds_read and its overwriting stage. Epilogue drains vmcnt 8->4->0.
template <int EPI>
__global__ __launch_bounds__(256) void gemm_bt(const u16* __restrict__ A,
                                               const u16* __restrict__ B,
                                               const float* __restrict__ bias,
                                               void* __restrict__ C,
                                               int M, int N, int K) {
  __shared__ u16 a_lds[4][128 * 32];
  __shared__ u16 b_lds[4][128 * 32];
  const int t = threadIdx.x;
  const int l = t & 63;
  const int w = t >> 6;
  const int wr = w >> 1, wc = w & 1;
  const int gxn = N >> 7;
  const int cpx = gridDim.x >> 3;
  const int swz = (blockIdx.x & 7) * cpx + (blockIdx.x >> 3);
  const int bm = (swz / gxn) * 128, bn = (swz % gxn) * 128;
  const int fl = l & 15, fh = l >> 4;
  const int NT = K >> 5;

  f32x4 acc[4][4] = {};

  const int srow = t >> 2;            // staged row 0..127 (chunk 0) / +... 
  const int scol = (t & 3) * 8;       // staged col chunk

#define STG(bb, kt)                                                            \
  {                                                                            \
    gl_lds16(A + (size_t)(bm + srow) * K + (kt) * 32 + scol,                   \
             &a_lds[bb][t * 8]);                                               \
    gl_lds16(A + (size_t)(bm + 64 + srow) * K + (kt) * 32 + scol,              \
             &a_lds[bb][(t + 256) * 8]);                                       \
    gl_lds16(B + (size_t)(bn + srow) * K + (kt) * 32 + scol,                   \
             &b_lds[bb][t * 8]);                                               \
    gl_lds16(B + (size_t)(bn + 64 + srow) * K + (kt) * 32 + scol,              \
             &b_lds[bb][(t + 256) * 8]);                                       \
  }

  STG(0, 0);
  STG(1, 1);
  STG(2, 2);

#define KBODY(tt, VMS)                                                         \
  {                                                                            \
    __builtin_amdgcn_sched_barrier(0);                                         \
    if ((tt) + 3 < NT) STG(((tt) + 3) & 3, (tt) + 3);                          \
    asm volatile("s_waitcnt vmcnt(" VMS ")" ::: "memory");                     \
    __builtin_amdgcn_sched_barrier(0);                                         \
    __builtin_amdgcn_s_barrier();                                              \
    __builtin_amdgcn_sched_barrier(0);                                         \
    const u16* ap = a_lds[(tt) & 3];                                           \
    const u16* bp = b_lds[(tt) & 3];                                           \
    bf16x8 af[4], bf[4];                                                       \
    _Pragma("unroll") for (int mi = 0; mi < 4; ++mi)                           \
        af[mi] = *(const bf16x8*)&ap[(wr * 64 + mi * 16 + fl) * 32 + fh * 8];  \
    _Pragma("unroll") for (int ni = 0; ni < 4; ++ni)                           \
        bf[ni] = *(const bf16x8*)&bp[(wc * 64 + ni * 16 + fl) * 32 + fh * 8];  \
    __builtin_amdgcn_s_setprio(1);                                             \
    _Pragma("unroll") for (int mi = 0; mi < 4; ++mi)                           \
        _Pragma("unroll") for (int ni = 0; ni < 4; ++ni)                       \
            acc[mi][ni] = __builtin_amdgcn_mfma_f32_16x16x32_bf16(             \
                af[mi], bf[ni], acc[mi][ni], 0, 0, 0);                         \
    __builtin_amdgcn_s_setprio(0);                                             \
    __builtin_amdgcn_sched_barrier(0);                                         \
    asm volatile("s_waitcnt lgkmcnt(0)" ::: "memory");                         \
    __builtin_amdgcn_sched_barrier(0);                                         \
    __builtin_amdgcn_s_barrier();                                              \
  }

  for (int ti = 0; ti < NT - 3; ++ti) KBODY(ti, "12");
  KBODY(NT - 3, "8");
  KBODY(NT - 2, "4");
  KBODY(NT - 1, "0");
#undef KBODY
#undef STG

#pragma unroll
  for (int mi = 0; mi < 4; ++mi) {
#pragma unroll
    for (int ni = 0; ni < 4; ++ni) {
      const int col = bn + wc * 64 + ni * 16 + fl;
      const float bv = bias ? bias[col] : 0.f;
#pragma unroll
      for (int r = 0; r < 4; ++r) {
        const int row = bm + wr * 64 + mi * 16 + fh * 4 + r;
        float v = acc[mi][ni][r] + bv;
        if (EPI == 0) {
          ((float*)C)[(size_t)row * N + col] = v;
        } else if (EPI == 1) {
          ((u16*)C)[(size_t)row * N + col] = f2bf(v);
        } else {
          ((u16*)C)[(size_t)row * N + col] = f2bf(fmaxf(v, 0.f));
        }
      }
    }
  }
}

// ---------------- V transpose: qkv v-section -> vT[bh][d][s] ----------------
__global__ __launch_bounds__(256) void transpose_v(const u16* __restrict__ qkv,
                                                   u16* __restrict__ vT) {
  __shared__ u16 tile[64][72];
  const int t = threadIdx.x;
  const int s0 = blockIdx.x * 64;
  const int bh = blockIdx.y, b = bh >> 4, h = bh & 15;
#pragma unroll
  for (int cc = 0; cc < 2; ++cc) {
    int idx = t + cc * 256, row = idx >> 3, c = idx & 7;
    *(bf16x8*)&tile[row][c * 8] = *(const bf16x8*)(
        qkv + (size_t)(b * SEQ + s0 + row) * 3072 + 2048 + h * 64 + c * 8);
  }
  __syncthreads();
#pragma unroll
  for (int cc = 0; cc < 2; ++cc) {
    int idx = t + cc * 256, drow = idx >> 3, c = idx & 7;
    u16x8 o;
#pragma unroll
    for (int j = 0; j < 8; ++j) o[j] = tile[c * 8 + j][drow];
    *(u16x8*)(vT + (size_t)(bh * 64 + drow) * SEQ + s0 + c * 8) = o;
  }
}

// ---------------- flash attention, KV-split, fixed-shift softmax ------------
__global__ __launch_bounds__(256, 4) void attn_kernel(const u16* __restrict__ qkv,
                                                      const u16* __restrict__ vT,
                                                      float* __restrict__ ctx) {
  __shared__ u16 smem[4][64 * 64];   // [hfv*2 + {K,V}][tile]  32KB
  __shared__ float mlbuf[2][2][32];  // [qg][hfv][q] : l partial

  const int t = threadIdx.x, l = t & 63, w = t >> 6;
  const int r0 = l & 31, hi = l >> 5, hib = hi * 16;
  const int qg = w >> 1, hfv = w & 1;

  const int id = blockIdx.x;
  const int swz = (id & 7) * 128 + (id >> 3);
  const int qblk = swz & 31;            // 32 q-blocks of 64 rows
  const int bh = swz >> 5;              // 32 (b,h) pairs
  const int b = bh >> 4, h = bh & 15;
  const int q0 = qblk * 64;
  const size_t rowbase = (size_t)b * SEQ;

  // Q fragments (B-operand: col = q = r0, k = d)
  bf16x8 qf[4];
#pragma unroll
  for (int kd = 0; kd < 4; ++kd)
    qf[kd] = *(const bf16x8*)(qkv +
        (rowbase + q0 + qg * 32 + r0) * 3072 + h * 64 + kd * 16 + hi * 8);

  f32x16 acc[2] = {};
  f32x16 lsum = {};
  const float C = 0.18033688011f;     // (1/8) * log2(e)
  const float SM0 = 20.0f * C;        // fixed shift (raw-score units * C)
  const short ONEB = (short)0x3F80;   // bf16 1.0
  const bf16x8 ones = {ONEB, ONEB, ONEB, ONEB, ONEB, ONEB, ONEB, ONEB};

  const u16* kb = smem[hfv * 2 + 0];
  const u16* vb = smem[hfv * 2 + 1];

  for (int s = 0; s < 16; ++s) {
    __syncthreads();
    // stage K/V tiles for BOTH halves (arr: 0=K0,1=V0,2=K1,3=V1)
#pragma unroll
    for (int cc = 0; cc < 8; ++cc) {
      const int i = t + cc * 256;
      const int arr = i >> 9;
      const int j = i & 511;
      const int rr = j >> 3, cb = (j & 7) * 16;
      const int sc_ = cb ^ ((rr & 7) << 4);
      const int hv = arr >> 1;
      u16* dst = &smem[arr][j * 8];
      if ((arr & 1) == 0)
        gl_lds16(qkv + (rowbase + hv * 1024 + s * 64 + rr) * 3072 + 1024 +
                     h * 64 + (sc_ >> 1), dst);
      else
        gl_lds16(vT + ((size_t)bh * 64 + rr) * SEQ + hv * 1024 + s * 64 +
                     (sc_ >> 1), dst);
    }
    __syncthreads();

    // QK^T (swapped): P^T[kv][q]
    f32x16 p0 = {}, p1 = {};
    __builtin_amdgcn_s_setprio(1);
#pragma unroll
    for (int kd = 0; kd < 4; ++kd) {
      const int cb = kd * 32 + hib;
      const uint8_t* pk = (const uint8_t*)kb;
      bf16x8 klo = *(const bf16x8*)(pk + r0 * 128 + (cb ^ ((r0 & 7) << 4)));
      bf16x8 khi = *(const bf16x8*)(pk + (r0 + 32) * 128 + (cb ^ ((r0 & 7) << 4)));
      p0 = mfma32(klo, qf[kd], p0);
      p1 = mfma32(khi, qf[kd], p1);
    }
    __builtin_amdgcn_s_setprio(0);

    // fixed-shift softmax: p = exp2(s*C - SM0). No max, no sum (see lsum).
#pragma unroll
    for (int i = 0; i < 16; ++i) {
      p0[i] = EXP2F(fmaf(p0[i], C, -SM0));
      p1[i] = EXP2F(fmaf(p1[i], C, -SM0));
    }

    // P -> bf16 B-fragments (T12)
    bf16x8 pb[4];
    {
      u32 c0, c1, c2, c3;
      u32x4 f;
      c0 = cvtpk(p0[0], p0[1]);   c1 = cvtpk(p0[2], p0[3]);
      c2 = cvtpk(p0[4], p0[5]);   c3 = cvtpk(p0[6], p0[7]);
      pl32swap(c0, c2); pl32swap(c1, c3);
      f[0] = c0; f[1] = c1; f[2] = c2; f[3] = c3; pb[0] = *(bf16x8*)&f;
      c0 = cvtpk(p0[8], p0[9]);   c1 = cvtpk(p0[10], p0[11]);
      c2 = cvtpk(p0[12], p0[13]); c3 = cvtpk(p0[14], p0[15]);
      pl32swap(c0, c2); pl32swap(c1, c3);
      f[0] = c0; f[1] = c1; f[2] = c2; f[3] = c3; pb[1] = *(bf16x8*)&f;
      c0 = cvtpk(p1[0], p1[1]);   c1 = cvtpk(p1[2], p1[3]);
      c2 = cvtpk(p1[4], p1[5]);   c3 = cvtpk(p1[6], p1[7]);
      pl32swap(c0, c2); pl32swap(c1, c3);
      f[0] = c0; f[1] = c1; f[2] = c2; f[3] = c3; pb[2] = *(bf16x8*)&f;
      c0 = cvtpk(p1[8], p1[9]);   c1 = cvtpk(p1[10], p1[11]);
      c2 = cvtpk(p1[12], p1[13]); c3 = cvtpk(p1[14], p1[15]);
      pl32swap(c0, c2); pl32swap(c1, c3);
      f[0] = c0; f[1] = c1; f[2] = c2; f[3] = c3; pb[3] = *(bf16x8*)&f;
    }

    // PV + l-accumulation (ones-trick) on the MFMA pipe
    __builtin_amdgcn_s_setprio(1);
#pragma unroll
    for (int ks = 0; ks < 4; ++ks)
      lsum = mfma32(ones, pb[ks], lsum);
#pragma unroll
    for (int dblk = 0; dblk < 2; ++dblk) {
#pragma unroll
      for (int ks = 0; ks < 4; ++ks) {
        const int rr = dblk * 32 + r0;
        const int cb = ks * 32 + hib;
        bf16x8 vf = *(const bf16x8*)((const uint8_t*)vb + rr * 128 +
                                     (cb ^ ((rr & 7) << 4)));
        acc[dblk] = mfma32(vf, pb[ks], acc[dblk]);
      }
    }
    __builtin_amdgcn_s_setprio(0);
  }

  // ---- merge of the two KV halves (shared shift -> just add) ----
  if (hi == 0) mlbuf[qg][hfv][r0] = lsum[0];
  __syncthreads();  // B1: l published; all smem compute done

  float* os = (float*)smem + qg * 32 * 68;  // union over smem, [q][d] pad 68
  if (hfv == 0) {
#pragma unroll
    for (int dblk = 0; dblk < 2; ++dblk)
#pragma unroll
      for (int i = 0; i < 16; ++i) {
        const int d = dblk * 32 + (i & 3) + 8 * (i >> 2) + 4 * hi;
        os[r0 * 68 + d] = acc[dblk][i];
      }
  }
  __syncthreads();  // B2: half-0 partial in place
  if (hfv == 1) {
#pragma unroll
    for (int dblk = 0; dblk < 2; ++dblk)
#pragma unroll
      for (int i = 0; i < 16; ++i) {
        const int d = dblk * 32 + (i & 3) + 8 * (i >> 2) + 4 * hi;
        os[r0 * 68 + d] += acc[dblk][i];
      }
#pragma unroll
    for (int it = 0; it < 8; ++it) {
      const int r = it * 4 + (l >> 4);
      const int c = (l & 15) * 4;
      const float inv = 1.f / (mlbuf[qg][0][r] + mlbuf[qg][1][r]);
      float4 v = *(const float4*)&os[r * 68 + c];
      v.x *= inv; v.y *= inv; v.z *= inv; v.w *= inv;
      *(float4*)&ctx[(rowbase + q0 + qg * 32 + r) * D_MODEL + h * 64 + c] = v;
    }
  }
}

// ---------------- residual + layernorm -------------------------------------
__global__ __launch_bounds__(256) void ln_kernel(const float* __restrict__ a,
                                                 const float* __restrict__ res,
                                                 const float* __restrict__ g,
                                                 const float* __restrict__ bta,
                                                 float* __restrict__ outf,
                                                 u16* __restrict__ outb) {
  __shared__ float sbuf[4];
  const int t = threadIdx.x;
  const size_t row = blockIdx.x;
  const float4 va = *(const float4*)(a + row * 1024 + t * 4);
  const float4 vr = *(const float4*)(res + row * 1024 + t * 4);
  float v[4] = {va.x + vr.x, va.y + vr.y, va.z + vr.z, va.w + vr.w};
  float s = v[0] + v[1] + v[2] + v[3];
#pragma unroll
  for (int m = 32; m; m >>= 1) s += __shfl_xor(s, m, 64);
  if ((t & 63) == 0) sbuf[t >> 6] = s;
  __syncthreads();
  const float mean = (sbuf[0] + sbuf[1] + sbuf[2] + sbuf[3]) * (1.f / 1024.f);
  float q = 0.f;
#pragma unroll
  for (int i = 0; i < 4; ++i) { v[i] -= mean; q += v[i] * v[i]; }
#pragma unroll
  for (int m = 32; m; m >>= 1) q += __shfl_xor(q, m, 64);
  __syncthreads();
  if ((t & 63) == 0) sbuf[t >> 6] = q;
  __syncthreads();
  const float var = (sbuf[0] + sbuf[1] + sbuf[2] + sbuf[3]) * (1.f / 1024.f);
  const float rs = rsqrtf(var + 1e-5f);
  const float4 vg = *(const float4*)(g + t * 4);
  const float4 vb = *(const float4*)(bta + t * 4);
  float o[4];
  o[0] = v[0] * rs * vg.x + vb.x;
  o[1] = v[1] * rs * vg.y + vb.y;
  o[2] = v[2] * rs * vg.z + vb.z;
  o[3] = v[3] * rs * vg.w + vb.w;
  float4 of = {o[0], o[1], o[2], o[3]};
  *(float4*)(outf + row * 1024 + t * 4) = of;
  if (outb) {
    u16x4 ob;
#pragma unroll
    for (int i = 0; i < 4; ++i) ob[i] = f2bf(o[i]);
    *(u16x4*)(outb + row * 1024 + t * 4) = ob;
  }
}

// ---------------- launch ----------------------------------------------------
extern "C" void kernel_launch(void* const* d_in, const int* in_sizes, int n_in,
                              void* d_out, int out_size, void* d_ws, size_t ws_size,
                              hipStream_t stream) {
  const float* x    = (const float*)d_in[0];
  const float* Wq   = (const float*)d_in[1];
  const float* bq   = (const float*)d_in[2];
  const float* Wk   = (const float*)d_in[3];
  const float* bk   = (const float*)d_in[4];
  const float* Wv   = (const float*)d_in[5];
  const float* bv   = (const float*)d_in[6];
  const float* ln_g = (const float*)d_in[7];
  const float* ln_b = (const float*)d_in[8];
  const float* W1   = (const float*)d_in[9];
  const float* b1   = (const float*)d_in[10];
  const float* W2   = (const float*)d_in[11];
  const float* b2   = (const float*)d_in[12];
  float* out = (float*)d_out;

  uint8_t* ws = (uint8_t*)d_ws;
  const size_t MB = 1 << 20;
  u16*   x_bf  = (u16*)  (ws + 0 * MB);
  u16*   wqkv  = (u16*)  (ws + 8 * MB);
  u16*   w1b   = (u16*)  (ws + 14 * MB);
  u16*   w2b   = (u16*)  (ws + 16 * MB);
  float* bqkv  = (float*)(ws + 18 * MB);
  u16*   qkv   = (u16*)  (ws + 19 * MB);
  u16*   vT    = (u16*)  (ws + 43 * MB);
  float* ctx   = (float*)(ws + 51 * MB);
  float* y     = (float*)(ws + 67 * MB);
  u16*   y_bf  = (u16*)  (ws + 83 * MB);
  u16*   h1    = (u16*)  (ws + 91 * MB);
  float* ffn   = (float*)(ws + 99 * MB);

  cvt_all<<<4609, 256, 0, stream>>>(x, Wq, Wk, Wv, W1, W2, bq, bk, bv,
                                    x_bf, wqkv, w1b, w2b, bqkv);
  gemm_bt<1><<<768, 256, 0, stream>>>(x_bf, wqkv, bqkv, qkv, NTOK, 3072, 1024);
  transpose_v<<<dim3(32, 32), 256, 0, stream>>>(qkv, vT);
  attn_kernel<<<1024, 256, 0, stream>>>(qkv, vT, ctx);
  ln_kernel<<<4096, 256, 0, stream>>>(ctx, x, ln_g, ln_b, y, y_bf);
  gemm_bt<2><<<256, 256, 0, stream>>>(y_bf, w1b, b1, h1, NTOK, 1024, 1024);
  gemm_bt<0><<<256, 256, 0, stream>>>(h1, w2b, b2, ffn, NTOK, 1024, 1024);
  ln_kernel<<<4096, 256, 0, stream>>>(ffn, y, ln_g, ln_b, out, nullptr);
}

// Round 8
// 251.964 us; speedup vs baseline: 1.1135x; 1.1135x over previous
//
#include <hip/hip_runtime.h>
#include <stdint.h>

#define D_MODEL 1024
#define NHEAD   16
#define HDIM    64
#define BATCH   2
#define SEQ     2048
#define NTOK    (BATCH*SEQ)   // 4096

typedef unsigned short u16;
typedef unsigned int   u32;
typedef __attribute__((ext_vector_type(8)))  short bf16x8;
typedef __attribute__((ext_vector_type(8)))  u16   u16x8;
typedef __attribute__((ext_vector_type(4)))  u16   u16x4;
typedef __attribute__((ext_vector_type(4)))  u32   u32x4;
typedef __attribute__((ext_vector_type(4)))  float f32x4;
typedef __attribute__((ext_vector_type(16))) float f32x16;

#if __has_builtin(__builtin_amdgcn_exp2f)
#define EXP2F __builtin_amdgcn_exp2f
#else
#define EXP2F exp2f
#endif

__device__ __forceinline__ u16 f2bf(float f) {
  uint32_t u = __float_as_uint(f);
  u += 0x7fffu + ((u >> 16) & 1u);
  return (u16)(u >> 16);
}

__device__ __forceinline__ void gl_lds16(const u16* g, u16* l) {
  __builtin_amdgcn_global_load_lds(
      (const __attribute__((address_space(1))) void*)g,
      (__attribute__((address_space(3))) void*)l, 16, 0, 0);
}

__device__ __forceinline__ u32 cvtpk(float lo, float hi) {
  u32 r;
  asm("v_cvt_pk_bf16_f32 %0, %1, %2" : "=v"(r) : "v"(lo), "v"(hi));
  return r;
}
__device__ __forceinline__ void pl32swap(u32& a, u32& b) {
  asm("v_permlane32_swap_b32 %0, %1" : "+v"(a), "+v"(b));
}

__device__ __forceinline__ f32x16 mfma32(bf16x8 a, bf16x8 b, f32x16 c) {
  return __builtin_amdgcn_mfma_f32_32x32x16_bf16(a, b, c, 0, 0, 0);
}

// ---------------- fused f32->bf16 convert for all 6 tensors + bias concat ---
__global__ __launch_bounds__(256) void cvt_all(
    const float* __restrict__ x,  const float* __restrict__ Wq,
    const float* __restrict__ Wk, const float* __restrict__ Wv,
    const float* __restrict__ W1, const float* __restrict__ W2,
    const float* __restrict__ bq, const float* __restrict__ bk,
    const float* __restrict__ bv,
    u16* __restrict__ x_bf, u16* __restrict__ wqkv,
    u16* __restrict__ w1b,  u16* __restrict__ w2b,
    float* __restrict__ bqkv) {
  const int bid = blockIdx.x, t = threadIdx.x;
  if (bid == 4608) {  // bias concat
    for (int i = t; i < 3072; i += 256)
      bqkv[i] = i < 1024 ? bq[i] : (i < 2048 ? bk[i - 1024] : bv[i - 2048]);
    return;
  }
  const float* src; u16* dst; int off;
  if (bid < 2048)      { src = x;  dst = x_bf;            off = bid; }
  else if (bid < 2560) { src = Wq; dst = wqkv;            off = bid - 2048; }
  else if (bid < 3072) { src = Wk; dst = wqkv + (1 << 20); off = bid - 2560; }
  else if (bid < 3584) { src = Wv; dst = wqkv + (2 << 20); off = bid - 3072; }
  else if (bid < 4096) { src = W1; dst = w1b;             off = bid - 3584; }
  else                 { src = W2; dst = w2b;             off = bid - 4096; }
  const int i = (off * 256 + t) * 8;
  float4 a = *(const float4*)(src + i);
  float4 b = *(const float4*)(src + i + 4);
  u16x8 o;
  o[0] = f2bf(a.x); o[1] = f2bf(a.y); o[2] = f2bf(a.z); o[3] = f2bf(a.w);
  o[4] = f2bf(b.x); o[5] = f2bf(b.y); o[6] = f2bf(b.z); o[7] = f2bf(b.w);
  *(u16x8*)(dst + i) = o;
}

// ---------------- BT GEMM: C[M,N] = A[M,K] * B[N,K]^T + bias ----------------
// 128x128 tile, BK=32, 2-phase dbuf (R6-proven). EPI 3 = QKV mode: Q/K cols
// -> bf16 qkv; V cols (>=2048) -> transposed into vT[bh][d][s] (8B chunks),
// eliminating the separate transpose kernel.
template <int EPI>
__global__ __launch_bounds__(256) void gemm_bt(const u16* __restrict__ A,
                                               const u16* __restrict__ B,
                                               const float* __restrict__ bias,
                                               void* __restrict__ C,
                                               u16* __restrict__ vT,
                                               int M, int N, int K) {
  __shared__ u16 a_lds[2][128 * 32];
  __shared__ u16 b_lds[2][128 * 32];
  const int t = threadIdx.x;
  const int l = t & 63;
  const int w = t >> 6;
  const int wr = w >> 1, wc = w & 1;
  const int gxn = N >> 7;
  const int cpx = gridDim.x >> 3;
  const int swz = (blockIdx.x & 7) * cpx + (blockIdx.x >> 3);
  const int bm = (swz / gxn) * 128, bn = (swz % gxn) * 128;
  const int fl = l & 15, fh = l >> 4;

  f32x4 acc[4][4] = {};

  const int row0 = t >> 2;
  const int row1 = (t + 256) >> 2;
  const int col0 = (t & 3) * 8;

#define GSTAGE(bb, kk)                                                         \
  gl_lds16(A + (size_t)(bm + row0) * K + (kk) + col0, &a_lds[bb][t * 8]);      \
  gl_lds16(A + (size_t)(bm + row1) * K + (kk) + col0,                          \
           &a_lds[bb][(t + 256) * 8]);                                         \
  gl_lds16(B + (size_t)(bn + row0) * K + (kk) + col0, &b_lds[bb][t * 8]);      \
  gl_lds16(B + (size_t)(bn + row1) * K + (kk) + col0,                          \
           &b_lds[bb][(t + 256) * 8]);

  GSTAGE(0, 0);
  __syncthreads();
  int cur = 0;

  for (int k0 = 0; k0 < K; k0 += 32) {
    if (k0 + 32 < K) { GSTAGE(cur ^ 1, k0 + 32); }

    bf16x8 af[4], bf[4];
#pragma unroll
    for (int mi = 0; mi < 4; ++mi)
      af[mi] = *(const bf16x8*)&a_lds[cur][(wr * 64 + mi * 16 + fl) * 32 + fh * 8];
#pragma unroll
    for (int ni = 0; ni < 4; ++ni)
      bf[ni] = *(const bf16x8*)&b_lds[cur][(wc * 64 + ni * 16 + fl) * 32 + fh * 8];
#pragma unroll
    for (int mi = 0; mi < 4; ++mi)
#pragma unroll
      for (int ni = 0; ni < 4; ++ni)
        acc[mi][ni] = __builtin_amdgcn_mfma_f32_16x16x32_bf16(
            af[mi], bf[ni], acc[mi][ni], 0, 0, 0);

    __syncthreads();
    cur ^= 1;
  }
#undef GSTAGE

#pragma unroll
  for (int mi = 0; mi < 4; ++mi) {
#pragma unroll
    for (int ni = 0; ni < 4; ++ni) {
      const int col = bn + wc * 64 + ni * 16 + fl;
      const float bv = bias ? bias[col] : 0.f;
      const int rowb = bm + wr * 64 + mi * 16 + fh * 4;
      if (EPI == 3 && col >= 2048) {
        // V column -> vT[(b*16+h)*64 + d][s], 4 consecutive s per thread
        const int hd = col - 2048;
        const int b_ = rowb >> 11, s_ = rowb & 2047;
        u16x4 ob;
#pragma unroll
        for (int r = 0; r < 4; ++r) ob[r] = f2bf(acc[mi][ni][r] + bv);
        *(u16x4*)(vT + ((size_t)(b_ * NHEAD + (hd >> 6)) * 64 + (hd & 63)) * SEQ
                      + s_) = ob;
      } else {
#pragma unroll
        for (int r = 0; r < 4; ++r) {
          const int row = rowb + r;
          float v = acc[mi][ni][r] + bv;
          if (EPI == 0) {
            ((float*)C)[(size_t)row * N + col] = v;
          } else if (EPI == 2) {
            ((u16*)C)[(size_t)row * N + col] = f2bf(fmaxf(v, 0.f));
          } else {  // 1 or 3(Q/K)
            ((u16*)C)[(size_t)row * N + col] = f2bf(v);
          }
        }
      }
    }
  }
}

// ---------------- FFN GEMM: BM=64 x BN=128, grid 512 (2 blocks/CU) ----------
// 4 warps as 1x4 col-strips (each 64x32). 2-phase dbuf, BK=32.
// EPI: 0 = f32 store, 2 = relu + bf16 store.
template <int EPI>
__global__ __launch_bounds__(256) void gemm_ffn(const u16* __restrict__ A,
                                                const u16* __restrict__ B,
                                                const float* __restrict__ bias,
                                                void* __restrict__ C,
                                                int M, int N, int K) {
  __shared__ u16 a_lds[2][64 * 32];
  __shared__ u16 b_lds[2][128 * 32];
  const int t = threadIdx.x;
  const int l = t & 63;
  const int w = t >> 6;
  const int gxn = N >> 7;
  const int cpx = gridDim.x >> 3;
  const int swz = (blockIdx.x & 7) * cpx + (blockIdx.x >> 3);
  const int bm = (swz / gxn) * 64, bn = (swz % gxn) * 128;
  const int fl = l & 15, fh = l >> 4;

  f32x4 acc[4][2] = {};

  const int arow = t >> 2;            // 0..63
  const int brow0 = t >> 2, brow1 = (t >> 2) + 64;
  const int col0 = (t & 3) * 8;

#define FSTAGE(bb, kk)                                                         \
  gl_lds16(A + (size_t)(bm + arow) * K + (kk) + col0, &a_lds[bb][t * 8]);      \
  gl_lds16(B + (size_t)(bn + brow0) * K + (kk) + col0, &b_lds[bb][t * 8]);     \
  gl_lds16(B + (size_t)(bn + brow1) * K + (kk) + col0,                         \
           &b_lds[bb][(t + 256) * 8]);

  FSTAGE(0, 0);
  __syncthreads();
  int cur = 0;

  for (int k0 = 0; k0 < K; k0 += 32) {
    if (k0 + 32 < K) { FSTAGE(cur ^ 1, k0 + 32); }

    bf16x8 af[4], bf[2];
#pragma unroll
    for (int mi = 0; mi < 4; ++mi)
      af[mi] = *(const bf16x8*)&a_lds[cur][(mi * 16 + fl) * 32 + fh * 8];
#pragma unroll
    for (int ni = 0; ni < 2; ++ni)
      bf[ni] = *(const bf16x8*)&b_lds[cur][(w * 32 + ni * 16 + fl) * 32 + fh * 8];
#pragma unroll
    for (int mi = 0; mi < 4; ++mi)
#pragma unroll
      for (int ni = 0; ni < 2; ++ni)
        acc[mi][ni] = __builtin_amdgcn_mfma_f32_16x16x32_bf16(
            af[mi], bf[ni], acc[mi][ni], 0, 0, 0);

    __syncthreads();
    cur ^= 1;
  }
#undef FSTAGE

#pragma unroll
  for (int mi = 0; mi < 4; ++mi) {
#pragma unroll
    for (int ni = 0; ni < 2; ++ni) {
      const int col = bn + w * 32 + ni * 16 + fl;
      const float bv = bias[col];
#pragma unroll
      for (int r = 0; r < 4; ++r) {
        const int row = bm + mi * 16 + fh * 4 + r;
        float v = acc[mi][ni][r] + bv;
        if (EPI == 0) {
          ((float*)C)[(size_t)row * N + col] = v;
        } else {
          ((u16*)C)[(size_t)row * N + col] = f2bf(fmaxf(v, 0.f));
        }
      }
    }
  }
}

// ---------------- flash attention, KV-split, fixed-shift softmax ------------
__global__ __launch_bounds__(256, 4) void attn_kernel(const u16* __restrict__ qkv,
                                                      const u16* __restrict__ vT,
                                                      float* __restrict__ ctx) {
  __shared__ u16 smem[4][64 * 64];   // [hfv*2 + {K,V}][tile]  32KB
  __shared__ float mlbuf[2][2][32];  // [qg][hfv][q] : l partial

  const int t = threadIdx.x, l = t & 63, w = t >> 6;
  const int r0 = l & 31, hi = l >> 5, hib = hi * 16;
  const int qg = w >> 1, hfv = w & 1;

  const int id = blockIdx.x;
  const int swz = (id & 7) * 128 + (id >> 3);
  const int qblk = swz & 31;            // 32 q-blocks of 64 rows
  const int bh = swz >> 5;              // 32 (b,h) pairs
  const int b = bh >> 4, h = bh & 15;
  const int q0 = qblk * 64;
  const size_t rowbase = (size_t)b * SEQ;

  // Q fragments (B-operand: col = q = r0, k = d)
  bf16x8 qf[4];
#pragma unroll
  for (int kd = 0; kd < 4; ++kd)
    qf[kd] = *(const bf16x8*)(qkv +
        (rowbase + q0 + qg * 32 + r0) * 3072 + h * 64 + kd * 16 + hi * 8);

  f32x16 acc[2] = {};
  f32x16 lsum = {};
  const float C = 0.18033688011f;     // (1/8) * log2(e)
  const float SM0 = 20.0f * C;        // fixed shift (raw-score units * C)
  const short ONEB = (short)0x3F80;   // bf16 1.0
  const bf16x8 ones = {ONEB, ONEB, ONEB, ONEB, ONEB, ONEB, ONEB, ONEB};

  const u16* kb = smem[hfv * 2 + 0];
  const u16* vb = smem[hfv * 2 + 1];

  for (int s = 0; s < 16; ++s) {
    __syncthreads();
    // stage K/V tiles for BOTH halves (arr: 0=K0,1=V0,2=K1,3=V1)
#pragma unroll
    for (int cc = 0; cc < 8; ++cc) {
      const int i = t + cc * 256;
      const int arr = i >> 9;
      const int j = i & 511;
      const int rr = j >> 3, cb = (j & 7) * 16;
      const int sc_ = cb ^ ((rr & 7) << 4);
      const int hv = arr >> 1;
      u16* dst = &smem[arr][j * 8];
      if ((arr & 1) == 0)
        gl_lds16(qkv + (rowbase + hv * 1024 + s * 64 + rr) * 3072 + 1024 +
                     h * 64 + (sc_ >> 1), dst);
      else
        gl_lds16(vT + ((size_t)bh * 64 + rr) * SEQ + hv * 1024 + s * 64 +
                     (sc_ >> 1), dst);
    }
    __syncthreads();

    // QK^T (swapped): P^T[kv][q]
    f32x16 p0 = {}, p1 = {};
    __builtin_amdgcn_s_setprio(1);
#pragma unroll
    for (int kd = 0; kd < 4; ++kd) {
      const int cb = kd * 32 + hib;
      const uint8_t* pk = (const uint8_t*)kb;
      bf16x8 klo = *(const bf16x8*)(pk + r0 * 128 + (cb ^ ((r0 & 7) << 4)));
      bf16x8 khi = *(const bf16x8*)(pk + (r0 + 32) * 128 + (cb ^ ((r0 & 7) << 4)));
      p0 = mfma32(klo, qf[kd], p0);
      p1 = mfma32(khi, qf[kd], p1);
    }
    __builtin_amdgcn_s_setprio(0);

    // fixed-shift softmax: p = exp2(s*C - SM0). No max, no sum (see lsum).
#pragma unroll
    for (int i = 0; i < 16; ++i) {
      p0[i] = EXP2F(fmaf(p0[i], C, -SM0));
      p1[i] = EXP2F(fmaf(p1[i], C, -SM0));
    }

    // P -> bf16 B-fragments (T12)
    bf16x8 pb[4];
    {
      u32 c0, c1, c2, c3;
      u32x4 f;
      c0 = cvtpk(p0[0], p0[1]);   c1 = cvtpk(p0[2], p0[3]);
      c2 = cvtpk(p0[4], p0[5]);   c3 = cvtpk(p0[6], p0[7]);
      pl32swap(c0, c2); pl32swap(c1, c3);
      f[0] = c0; f[1] = c1; f[2] = c2; f[3] = c3; pb[0] = *(bf16x8*)&f;
      c0 = cvtpk(p0[8], p0[9]);   c1 = cvtpk(p0[10], p0[11]);
      c2 = cvtpk(p0[12], p0[13]); c3 = cvtpk(p0[14], p0[15]);
      pl32swap(c0, c2); pl32swap(c1, c3);
      f[0] = c0; f[1] = c1; f[2] = c2; f[3] = c3; pb[1] = *(bf16x8*)&f;
      c0 = cvtpk(p1[0], p1[1]);   c1 = cvtpk(p1[2], p1[3]);
      c2 = cvtpk(p1[4], p1[5]);   c3 = cvtpk(p1[6], p1[7]);
      pl32swap(c0, c2); pl32swap(c1, c3);
      f[0] = c0; f[1] = c1; f[2] = c2; f[3] = c3; pb[2] = *(bf16x8*)&f;
      c0 = cvtpk(p1[8], p1[9]);   c1 = cvtpk(p1[10], p1[11]);
      c2 = cvtpk(p1[12], p1[13]); c3 = cvtpk(p1[14], p1[15]);
      pl32swap(c0, c2); pl32swap(c1, c3);
      f[0] = c0; f[1] = c1; f[2] = c2; f[3] = c3; pb[3] = *(bf16x8*)&f;
    }

    // PV + l-accumulation (ones-trick) on the MFMA pipe
    __builtin_amdgcn_s_setprio(1);
#pragma unroll
    for (int ks = 0; ks < 4; ++ks)
      lsum = mfma32(ones, pb[ks], lsum);
#pragma unroll
    for (int dblk = 0; dblk < 2; ++dblk) {
#pragma unroll
      for (int ks = 0; ks < 4; ++ks) {
        const int rr = dblk * 32 + r0;
        const int cb = ks * 32 + hib;
        bf16x8 vf = *(const bf16x8*)((const uint8_t*)vb + rr * 128 +
                                     (cb ^ ((rr & 7) << 4)));
        acc[dblk] = mfma32(vf, pb[ks], acc[dblk]);
      }
    }
    __builtin_amdgcn_s_setprio(0);
  }

  // ---- merge of the two KV halves (shared shift -> just add) ----
  if (hi == 0) mlbuf[qg][hfv][r0] = lsum[0];
  __syncthreads();  // B1: l published; all smem compute done

  float* os = (float*)smem + qg * 32 * 68;  // union over smem, [q][d] pad 68
  if (hfv == 0) {
#pragma unroll
    for (int dblk = 0; dblk < 2; ++dblk)
#pragma unroll
      for (int i = 0; i < 16; ++i) {
        const int d = dblk * 32 + (i & 3) + 8 * (i >> 2) + 4 * hi;
        os[r0 * 68 + d] = acc[dblk][i];
      }
  }
  __syncthreads();  // B2: half-0 partial in place
  if (hfv == 1) {
#pragma unroll
    for (int dblk = 0; dblk < 2; ++dblk)
#pragma unroll
      for (int i = 0; i < 16; ++i) {
        const int d = dblk * 32 + (i & 3) + 8 * (i >> 2) + 4 * hi;
        os[r0 * 68 + d] += acc[dblk][i];
      }
#pragma unroll
    for (int it = 0; it < 8; ++it) {
      const int r = it * 4 + (l >> 4);
      const int c = (l & 15) * 4;
      const float inv = 1.f / (mlbuf[qg][0][r] + mlbuf[qg][1][r]);
      float4 v = *(const float4*)&os[r * 68 + c];
      v.x *= inv; v.y *= inv; v.z *= inv; v.w *= inv;
      *(float4*)&ctx[(rowbase + q0 + qg * 32 + r) * D_MODEL + h * 64 + c] = v;
    }
  }
}

// ---------------- residual + layernorm -------------------------------------
__global__ __launch_bounds__(256) void ln_kernel(const float* __restrict__ a,
                                                 const float* __restrict__ res,
                                                 const float* __restrict__ g,
                                                 const float* __restrict__ bta,
                                                 float* __restrict__ outf,
                                                 u16* __restrict__ outb) {
  __shared__ float sbuf[4];
  const int t = threadIdx.x;
  const size_t row = blockIdx.x;
  const float4 va = *(const float4*)(a + row * 1024 + t * 4);
  const float4 vr = *(const float4*)(res + row * 1024 + t * 4);
  float v[4] = {va.x + vr.x, va.y + vr.y, va.z + vr.z, va.w + vr.w};
  float s = v[0] + v[1] + v[2] + v[3];
#pragma unroll
  for (int m = 32; m; m >>= 1) s += __shfl_xor(s, m, 64);
  if ((t & 63) == 0) sbuf[t >> 6] = s;
  __syncthreads();
  const float mean = (sbuf[0] + sbuf[1] + sbuf[2] + sbuf[3]) * (1.f / 1024.f);
  float q = 0.f;
#pragma unroll
  for (int i = 0; i < 4; ++i) { v[i] -= mean; q += v[i] * v[i]; }
#pragma unroll
  for (int m = 32; m; m >>= 1) q += __shfl_xor(q, m, 64);
  __syncthreads();
  if ((t & 63) == 0) sbuf[t >> 6] = q;
  __syncthreads();
  const float var = (sbuf[0] + sbuf[1] + sbuf[2] + sbuf[3]) * (1.f / 1024.f);
  const float rs = rsqrtf(var + 1e-5f);
  const float4 vg = *(const float4*)(g + t * 4);
  const float4 vb = *(const float4*)(bta + t * 4);
  float o[4];
  o[0] = v[0] * rs * vg.x + vb.x;
  o[1] = v[1] * rs * vg.y + vb.y;
  o[2] = v[2] * rs * vg.z + vb.z;
  o[3] = v[3] * rs * vg.w + vb.w;
  float4 of = {o[0], o[1], o[2], o[3]};
  *(float4*)(outf + row * 1024 + t * 4) = of;
  if (outb) {
    u16x4 ob;
#pragma unroll
    for (int i = 0; i < 4; ++i) ob[i] = f2bf(o[i]);
    *(u16x4*)(outb + row * 1024 + t * 4) = ob;
  }
}

// ---------------- launch ----------------------------------------------------
extern "C" void kernel_launch(void* const* d_in, const int* in_sizes, int n_in,
                              void* d_out, int out_size, void* d_ws, size_t ws_size,
                              hipStream_t stream) {
  const float* x    = (const float*)d_in[0];
  const float* Wq   = (const float*)d_in[1];
  const float* bq   = (const float*)d_in[2];
  const float* Wk   = (const float*)d_in[3];
  const float* bk   = (const float*)d_in[4];
  const float* Wv   = (const float*)d_in[5];
  const float* bv   = (const float*)d_in[6];
  const float* ln_g = (const float*)d_in[7];
  const float* ln_b = (const float*)d_in[8];
  const float* W1   = (const float*)d_in[9];
  const float* b1   = (const float*)d_in[10];
  const float* W2   = (const float*)d_in[11];
  const float* b2   = (const float*)d_in[12];
  float* out = (float*)d_out;

  uint8_t* ws = (uint8_t*)d_ws;
  const size_t MB = 1 << 20;
  u16*   x_bf  = (u16*)  (ws + 0 * MB);
  u16*   wqkv  = (u16*)  (ws + 8 * MB);
  u16*   w1b   = (u16*)  (ws + 14 * MB);
  u16*   w2b   = (u16*)  (ws + 16 * MB);
  float* bqkv  = (float*)(ws + 18 * MB);
  u16*   qkv   = (u16*)  (ws + 19 * MB);
  u16*   vT    = (u16*)  (ws + 43 * MB);
  float* ctx   = (float*)(ws + 51 * MB);
  float* y     = (float*)(ws + 67 * MB);
  u16*   y_bf  = (u16*)  (ws + 83 * MB);
  u16*   h1    = (u16*)  (ws + 91 * MB);
  float* ffn   = (float*)(ws + 99 * MB);

  cvt_all<<<4609, 256, 0, stream>>>(x, Wq, Wk, Wv, W1, W2, bq, bk, bv,
                                    x_bf, wqkv, w1b, w2b, bqkv);
  // QKV projection; V written transposed straight into vT
  gemm_bt<3><<<768, 256, 0, stream>>>(x_bf, wqkv, bqkv, qkv, vT,
                                      NTOK, 3072, 1024);
  attn_kernel<<<1024, 256, 0, stream>>>(qkv, vT, ctx);
  ln_kernel<<<4096, 256, 0, stream>>>(ctx, x, ln_g, ln_b, y, y_bf);
  gemm_ffn<2><<<512, 256, 0, stream>>>(y_bf, w1b, b1, h1, NTOK, 1024, 1024);
  gemm_ffn<0><<<512, 256, 0, stream>>>(h1, w2b, b2, ffn, NTOK, 1024, 1024);
  ln_kernel<<<4096, 256, 0, stream>>>(ffn, y, ln_g, ln_b, out, nullptr);
}